// Round 5
// baseline (319.095 us; speedup 1.0000x reference)
//
#include <hip/hip_runtime.h>
#include <hip/hip_bf16.h>

typedef __bf16 bf16x8 __attribute__((ext_vector_type(8)));
typedef float  f32x4  __attribute__((ext_vector_type(4)));
typedef float  f32x16 __attribute__((ext_vector_type(16)));
typedef __attribute__((address_space(3))) char* lds3_t;

#define M_DIM 8192
#define N_DIM 4096
#define K_DIM 4096
#define NG    32
#define KHALF (K_DIM / 2)

// ---------------- prep: A fp32 -> bf16 (vectorized) ------------------------
__global__ __launch_bounds__(256) void cvtA_kernel(const float* __restrict__ A,
                                                   __bf16* __restrict__ Ab,
                                                   long n8) {
    long i = (long)blockIdx.x * blockDim.x + threadIdx.x;
    long stride = (long)gridDim.x * blockDim.x;
    const float4* A4 = (const float4*)A;
    for (long p = i; p < n8; p += stride) {
        float4 v0 = A4[2 * p];
        float4 v1 = A4[2 * p + 1];
        bf16x8 o;
        o[0] = (__bf16)v0.x; o[1] = (__bf16)v0.y;
        o[2] = (__bf16)v0.z; o[3] = (__bf16)v0.w;
        o[4] = (__bf16)v1.x; o[5] = (__bf16)v1.y;
        o[6] = (__bf16)v1.z; o[7] = (__bf16)v1.w;
        *(bf16x8*)(Ab + p * 8) = o;
    }
}

// ---------------- prep: unpack int4 + dequant -> W bf16 [N, K] -------------
__global__ __launch_bounds__(256) void deqW_kernel(const int* __restrict__ qw,
                                                   const float* __restrict__ sc,
                                                   const float* __restrict__ zr,
                                                   __bf16* __restrict__ Wb) {
    long i = (long)blockIdx.x * blockDim.x + threadIdx.x;
    long stride = (long)gridDim.x * blockDim.x;
    const long nch = (long)N_DIM * (KHALF / 4);
    const int4* q4 = (const int4*)qw;
    for (long p = i; p < nch; p += stride) {
        int n  = (int)(p >> 9);
        int cj = (int)(p & 511);
        int i0 = cj * 4;
        int g  = i0 >> 6;
        float s = sc[n * NG + g];
        float z = zr[n * NG + g];
        int4 qv = q4[p];
        bf16x8 o;
        int b;
        b = qv.x; o[0] = (__bf16)(((float)(b & 0xF) - z) * s);
                  o[1] = (__bf16)(((float)((b >> 4) & 0xF) - z) * s);
        b = qv.y; o[2] = (__bf16)(((float)(b & 0xF) - z) * s);
                  o[3] = (__bf16)(((float)((b >> 4) & 0xF) - z) * s);
        b = qv.z; o[4] = (__bf16)(((float)(b & 0xF) - z) * s);
                  o[5] = (__bf16)(((float)((b >> 4) & 0xF) - z) * s);
        b = qv.w; o[6] = (__bf16)(((float)(b & 0xF) - z) * s);
                  o[7] = (__bf16)(((float)((b >> 4) & 0xF) - z) * s);
        *(bf16x8*)(Wb + (long)n * K_DIM + i0 * 2) = o;
    }
}

// ---------------- main GEMM: 256x256, BK=64, 8-wave, snake, 32x32x16 -------
// Round-5 change: swizzle now slot = chunk ^ (row&7) ^ (((row>>4)&1)<<2)
// (row bit 4 added on BOTH staging-source and read sides) — fixes the 2-way
// bank conflict from HW co-scheduling lanes 16 apart on ds_read_b128.
#define BM 256
#define BN 256
#define BK 64
#define NT (K_DIM / BK)   // 64

#define SB0 __builtin_amdgcn_sched_barrier(0)
#define BAR do { SB0; __builtin_amdgcn_s_barrier(); } while (0)
#define LGKM(N) do { asm volatile("s_waitcnt lgkmcnt(" #N ")" ::: "memory"); SB0; } while (0)
#define VMW(N)  do { asm volatile("s_waitcnt vmcnt(" #N ")"  ::: "memory"); SB0; } while (0)
#define PRIO1 __builtin_amdgcn_s_setprio(1)
#define PRIO0 __builtin_amdgcn_s_setprio(0)

// ds_read_b128 at (base XOR XR) + OFFS. XR in {0,32,64,96} = ks<<5.
#define DSRX(dst, base, XR, OFFS)                                        \
  do {                                                                   \
    unsigned _t_;                                                        \
    asm volatile("v_xor_b32 %1, " XR ", %2\n\t"                          \
                 "ds_read_b128 %0, %1 offset:" OFFS                      \
                 : "=v"(dst), "=&v"(_t_) : "v"(base));                   \
  } while (0)

// A half-read: 4 b128 = (mb0,ks0)(mb0,ks1)(mb1,ks0)(mb1,ks1)
#define RD_A(BASE, Q, K, X0, X1, O0, O1)           \
  do {                                             \
    DSRX(a##Q##k##K[0], BASE, X0, O0);             \
    DSRX(a##Q##k##K[1], BASE, X1, O0);             \
    DSRX(a##Q##k##K[2], BASE, X0, O1);             \
    DSRX(a##Q##k##K[3], BASE, X1, O1);             \
  } while (0)

// B block-read: 2 b128 = (nb,ks0)(nb,ks1)
#define RD_B(BASE, Q, K, X0, X1, ON)               \
  do {                                             \
    DSRX(b##Q##k##K[0], BASE, X0, ON);             \
    DSRX(b##Q##k##K[1], BASE, X1, ON);             \
  } while (0)

// 4 MFMA, two chains interleaved (acc0, acc1, acc0, acc1) for issue distance
#define MFMA4(QM, QN, KK)                                                          \
  do {                                                                             \
    PRIO1;                                                                         \
    acc[(QM) * 2 + 0][QN] = __builtin_amdgcn_mfma_f32_32x32x16_bf16(               \
        a##QM##k##KK[0], b##QN##k##KK[0], acc[(QM) * 2 + 0][QN], 0, 0, 0);         \
    acc[(QM) * 2 + 1][QN] = __builtin_amdgcn_mfma_f32_32x32x16_bf16(               \
        a##QM##k##KK[2], b##QN##k##KK[0], acc[(QM) * 2 + 1][QN], 0, 0, 0);         \
    acc[(QM) * 2 + 0][QN] = __builtin_amdgcn_mfma_f32_32x32x16_bf16(               \
        a##QM##k##KK[1], b##QN##k##KK[1], acc[(QM) * 2 + 0][QN], 0, 0, 0);         \
    acc[(QM) * 2 + 1][QN] = __builtin_amdgcn_mfma_f32_32x32x16_bf16(               \
        a##QM##k##KK[3], b##QN##k##KK[1], acc[(QM) * 2 + 1][QN], 0, 0, 0);         \
    PRIO0;                                                                         \
  } while (0)

// stage one half-tile (2 x global_load_lds dwordx4)
#define STAGE(SRC, MATOFF, H, DB, KT)                                                              \
  do {                                                                                             \
    __builtin_amdgcn_global_load_lds(                                                              \
        (__attribute__((address_space(1))) void*)((SRC) + (long)((H) * 128) * (K_DIM * 2) +        \
                                                  (long)(KT) * (BK * 2)),                          \
        (__attribute__((address_space(3))) void*)(lds + (DB) + (MATOFF) + (H) * 16384 + ldst),     \
        16, 0, 0);                                                                                 \
    __builtin_amdgcn_global_load_lds(                                                              \
        (__attribute__((address_space(1))) void*)((SRC) + (long)((H) * 128 + 64) * (K_DIM * 2) +   \
                                                  (long)(KT) * (BK * 2)),                          \
        (__attribute__((address_space(3))) void*)(lds + (DB) + (MATOFF) + (H) * 16384 + 8192 +     \
                                                  ldst),                                           \
        16, 0, 0);                                                                                 \
  } while (0)

// One K-tile, parity P (literal 0/1), next parity PN.
#define TILE(P, PN, JJ)                                                           \
  do {                                                                            \
    const int jp1 = (JJ) + 1, jp2 = (JJ) + 2;                                     \
    /* ph1: MFMA(0,0,k0); read A1k0; stage B-h0(j+1) */                           \
    BAR;                                                                          \
    RD_A(aa##P, 1, 0, "0", "32", "8192", "12288");                                \
    if (jp1 < NT) STAGE(Bsrc, 32768, 0, (PN) * 65536, jp1);                       \
    LGKM(4);                                                                      \
    MFMA4(0, 0, 0);                                                               \
    /* ph2: MFMA(1,0,k0); read B1k0; stage B-h1(j+1) */                           \
    BAR;                                                                          \
    RD_B(ba##P, 1, 0, "0", "32", "4096");                                         \
    if (jp1 < NT) STAGE(Bsrc, 32768, 1, (PN) * 65536, jp1);                       \
    LGKM(2);                                                                      \
    MFMA4(1, 0, 0);                                                               \
    /* ph3: MFMA(1,1,k0) */                                                       \
    BAR;                                                                          \
    LGKM(0);                                                                      \
    MFMA4(1, 1, 0);                                                               \
    /* ph4: MFMA(0,1,k0); read A0k1 + B1k1 */                                     \
    BAR;                                                                          \
    RD_A(aa##P, 0, 1, "64", "96", "0", "4096");                                   \
    RD_B(ba##P, 1, 1, "64", "96", "4096");                                        \
    LGKM(6);                                                                      \
    MFMA4(0, 1, 0);                                                               \
    /* ph5: MFMA(0,1,k1); read A1k1 */                                            \
    BAR;                                                                          \
    RD_A(aa##P, 1, 1, "64", "96", "8192", "12288");                               \
    LGKM(4);                                                                      \
    MFMA4(0, 1, 1);                                                               \
    /* ph6: MFMA(1,1,k1); read B0k1 */                                            \
    BAR;                                                                          \
    RD_B(ba##P, 0, 1, "64", "96", "0");                                           \
    LGKM(2);                                                                      \
    MFMA4(1, 1, 1);                                                               \
    /* ph7: MFMA(1,0,k1); stage A-h0(j+2); vmcnt */                               \
    BAR;                                                                          \
    LGKM(0);                                                                      \
    if (jp2 < NT) {                                                               \
      STAGE(Asrc, 0, 0, (P) * 65536, jp2);                                        \
      VMW(2);                                                                     \
    } else {                                                                      \
      VMW(0);                                                                     \
    }                                                                             \
    MFMA4(1, 0, 1);                                                               \
    /* ph8: MFMA(0,0,k1); read next-tile A0k0,B0k0 (parity PN); stage A-h1 */     \
    BAR;                                                                          \
    RD_A(aa##PN, 0, 0, "0", "32", "0", "4096");                                   \
    RD_B(ba##PN, 0, 0, "0", "32", "0");                                           \
    if (jp2 < NT) STAGE(Asrc, 0, 1, (P) * 65536, jp2);                            \
    LGKM(6);                                                                      \
    MFMA4(0, 0, 1);                                                               \
  } while (0)

__global__ __launch_bounds__(512, 2) void gemm8p(const __bf16* __restrict__ A,
                                                 const __bf16* __restrict__ B,
                                                 float* __restrict__ C) {
    __shared__ __attribute__((aligned(128))) char lds[131072];

    // XCD-aware bijective swizzle: nwg = 512, divisible by 8
    const int nwg = (M_DIM / BM) * (N_DIM / BN);   // 512
    int bid = blockIdx.x;
    int sw  = (bid & 7) * (nwg >> 3) + (bid >> 3);
    int mt = sw >> 4, ntl = sw & 15;               // 32 x 16 tiles
    int bm0 = mt * BM, bn0 = ntl * BN;

    int tid  = threadIdx.x;
    int lane = tid & 63;
    int wid  = tid >> 6;
    int wr   = wid >> 2;      // 0..1  (M half)
    int wc   = wid & 3;       // 0..3  (N quarter)

    f32x16 acc[4][2];
#pragma unroll
    for (int m = 0; m < 4; ++m)
#pragma unroll
        for (int n = 0; n < 2; ++n)
#pragma unroll
            for (int r = 0; r < 16; ++r) acc[m][n][r] = 0.f;

    // fragment registers (single-buffered; snake order makes WAR legal)
    bf16x8 a0k0[4], a1k0[4], a0k1[4], a1k1[4];
    bf16x8 b0k0[2], b1k0[2], b0k1[2], b1k1[2];

    // ---- staging addressing (inverse-swizzled global source, linear dest) ----
    // slot = chunk ^ (row&7) ^ (((row>>4)&1)<<2)  [row bit 4 breaks the
    // lane/lane+16 co-schedule conflict]
    int srow  = tid >> 3;
    int scolb = ((tid & 7) ^ (srow & 7) ^ (((srow >> 4) & 1) << 2)) * 16;
    const char* Asrc = (const char*)(A + (long)(bm0 + srow) * K_DIM) + scolb;
    const char* Bsrc = (const char*)(B + (long)(bn0 + srow) * K_DIM) + scolb;
    int ldst = tid * 16;

    // ---- fragment-read addressing (32x32x16) ----
    // lane: row = l&31, k = (l>>5)*8 + e. chunk(ks) = ks*2 + (l>>5);
    // slot = chunk ^ (row&7) ^ (((row>>4)&1)<<2); row bit4 == lane bit4 for
    // every sub-tile offset (all offsets shift rows by multiples of 32).
    int cs0  = ((((lane >> 5) ^ (lane & 7)) ^ (((lane >> 4) & 1) << 2)) << 4);
    int arow = (lane & 31) * 128;
    lds3_t aa0 = (lds3_t)(lds + wr * 16384 + arow + cs0);
    lds3_t aa1 = (lds3_t)(lds + 65536 + wr * 16384 + arow + cs0);
    lds3_t ba0 = (lds3_t)(lds + 32768 + wc * 8192 + arow + cs0);
    lds3_t ba1 = (lds3_t)(lds + 65536 + 32768 + wc * 8192 + arow + cs0);

    // ---- prologue: stage tile0 (all) + tile1 (A halves); then first reads ----
    STAGE(Asrc, 0,     0, 0, 0);
    STAGE(Asrc, 0,     1, 0, 0);
    STAGE(Bsrc, 32768, 0, 0, 0);
    STAGE(Bsrc, 32768, 1, 0, 0);
    STAGE(Asrc, 0,     0, 65536, 1);
    STAGE(Asrc, 0,     1, 65536, 1);
    VMW(4);                               // tile0 landed; tile1-A in flight
    BAR;
    RD_A(aa0, 0, 0, "0", "32", "0", "4096");   // A0k0(0)
    RD_B(ba0, 0, 0, "0", "32", "0");           // B0k0(0)

    for (int j = 0; j < NT; j += 2) {
        TILE(0, 1, j);
        TILE(1, 0, j + 1);
    }

    // ---- epilogue: 32x32 C/D: col = lane&31, row = (r&3)+8*(r>>2)+4*(l>>5) ----
    int crow0 = bm0 + wr * 128 + ((lane >> 5) << 2);
    int ccol0 = bn0 + wc * 64 + (lane & 31);
#pragma unroll
    for (int mb = 0; mb < 4; ++mb)
#pragma unroll
        for (int nb = 0; nb < 2; ++nb)
#pragma unroll
            for (int r = 0; r < 16; ++r) {
                int row = mb * 32 + (r & 3) + ((r >> 2) << 3);
                C[(long)(crow0 + row) * N_DIM + (ccol0 + nb * 32)] = acc[mb][nb][r];
            }
}

// ---------------- fallback (only if ws too small): fused naive -------------
__global__ __launch_bounds__(256) void gemm_fallback(const float* __restrict__ A,
                                                     const int* __restrict__ qw,
                                                     const float* __restrict__ sc,
                                                     const float* __restrict__ zr,
                                                     float* __restrict__ C) {
    __shared__ float Ash[16][17];
    __shared__ float Wsh[16][17];
    int tx = threadIdx.x & 15, ty = threadIdx.x >> 4;
    int m = blockIdx.y * 16 + ty;
    int n = blockIdx.x * 16 + tx;
    float s = 0.f;
    for (int k0 = 0; k0 < K_DIM; k0 += 16) {
        Ash[ty][tx] = A[(long)m * K_DIM + k0 + tx];
        {
            int nn = blockIdx.x * 16 + ty;
            int kk = k0 + tx;
            int q = qw[(long)nn * KHALF + (kk >> 1)];
            int nib = (kk & 1) ? ((q >> 4) & 0xF) : (q & 0xF);
            int g = kk >> 7;
            Wsh[ty][tx] = ((float)nib - zr[nn * NG + g]) * sc[nn * NG + g];
        }
        __syncthreads();
#pragma unroll
        for (int kk = 0; kk < 16; ++kk)
            s += Ash[ty][kk] * Wsh[tx][kk];
        __syncthreads();
    }
    C[(long)m * N_DIM + n] = s;
}

extern "C" void kernel_launch(void* const* d_in, const int* in_sizes, int n_in,
                              void* d_out, int out_size, void* d_ws, size_t ws_size,
                              hipStream_t stream) {
    const float* A  = (const float*)d_in[0];
    const int*   qw = (const int*)d_in[1];
    const float* sc = (const float*)d_in[2];
    const float* zr = (const float*)d_in[3];
    float* C = (float*)d_out;

    const size_t needA = (size_t)M_DIM * K_DIM * 2;   // 64 MiB
    const size_t needW = (size_t)N_DIM * K_DIM * 2;   // 32 MiB

    if (ws_size >= needA + needW) {
        __bf16* Ab = (__bf16*)d_ws;
        __bf16* Wb = (__bf16*)((char*)d_ws + needA);
        cvtA_kernel<<<2048, 256, 0, stream>>>(A, Ab, (long)M_DIM * K_DIM / 8);
        deqW_kernel<<<2048, 256, 0, stream>>>(qw, sc, zr, Wb);
        gemm8p<<<(M_DIM / BM) * (N_DIM / BN), 512, 0, stream>>>(Ab, Wb, C);
    } else {
        dim3 g(N_DIM / 16, M_DIM / 16);
        gemm_fallback<<<g, 256, 0, stream>>>(A, qw, sc, zr, C);
    }
}

// Round 6
// 271.455 us; speedup vs baseline: 1.1755x; 1.1755x over previous
//
#include <hip/hip_runtime.h>
#include <hip/hip_bf16.h>

typedef __bf16 bf16x8 __attribute__((ext_vector_type(8)));
typedef float  f32x4  __attribute__((ext_vector_type(4)));
typedef __attribute__((address_space(3))) char* lds3_t;

#define M_DIM 8192
#define N_DIM 4096
#define K_DIM 4096
#define NG    32
#define KHALF (K_DIM / 2)

// ---------------- prep: A fp32 -> bf16 (vectorized) ------------------------
__global__ __launch_bounds__(256) void cvtA_kernel(const float* __restrict__ A,
                                                   __bf16* __restrict__ Ab,
                                                   long n8) {
    long i = (long)blockIdx.x * blockDim.x + threadIdx.x;
    long stride = (long)gridDim.x * blockDim.x;
    const float4* A4 = (const float4*)A;
    for (long p = i; p < n8; p += stride) {
        float4 v0 = A4[2 * p];
        float4 v1 = A4[2 * p + 1];
        bf16x8 o;
        o[0] = (__bf16)v0.x; o[1] = (__bf16)v0.y;
        o[2] = (__bf16)v0.z; o[3] = (__bf16)v0.w;
        o[4] = (__bf16)v1.x; o[5] = (__bf16)v1.y;
        o[6] = (__bf16)v1.z; o[7] = (__bf16)v1.w;
        *(bf16x8*)(Ab + p * 8) = o;
    }
}

// ---------------- prep: unpack int4 + dequant -> W bf16 [N, K] -------------
__global__ __launch_bounds__(256) void deqW_kernel(const int* __restrict__ qw,
                                                   const float* __restrict__ sc,
                                                   const float* __restrict__ zr,
                                                   __bf16* __restrict__ Wb) {
    long i = (long)blockIdx.x * blockDim.x + threadIdx.x;
    long stride = (long)gridDim.x * blockDim.x;
    const long nch = (long)N_DIM * (KHALF / 4);
    const int4* q4 = (const int4*)qw;
    for (long p = i; p < nch; p += stride) {
        int n  = (int)(p >> 9);
        int cj = (int)(p & 511);
        int i0 = cj * 4;
        int g  = i0 >> 6;
        float s = sc[n * NG + g];
        float z = zr[n * NG + g];
        int4 qv = q4[p];
        bf16x8 o;
        int b;
        b = qv.x; o[0] = (__bf16)(((float)(b & 0xF) - z) * s);
                  o[1] = (__bf16)(((float)((b >> 4) & 0xF) - z) * s);
        b = qv.y; o[2] = (__bf16)(((float)(b & 0xF) - z) * s);
                  o[3] = (__bf16)(((float)((b >> 4) & 0xF) - z) * s);
        b = qv.z; o[4] = (__bf16)(((float)(b & 0xF) - z) * s);
                  o[5] = (__bf16)(((float)((b >> 4) & 0xF) - z) * s);
        b = qv.w; o[6] = (__bf16)(((float)(b & 0xF) - z) * s);
                  o[7] = (__bf16)(((float)((b >> 4) & 0xF) - z) * s);
        *(bf16x8*)(Wb + (long)n * K_DIM + i0 * 2) = o;
    }
}

// ---------------- main GEMM: 256x256, BK=64, 8-wave, snake, 16x16x32 -------
// Round-6: round-3 base (16x16x32, XOR swizzle slot=chunk^(row&7), 0 conflicts)
// with: 2-phase read lead (reads issued 2 phases before their MFMA), exact
// counted lgkm waits {6,2,6,-,6,2,6,-}, 4 barriers/tile (epochs of 2 phases),
// single VMW(0)/tile at ph6 draining loads >=4 phases old (exact ledger).
#define BM 256
#define BN 256
#define BK 64
#define NT (K_DIM / BK)   // 64

#define SB0 __builtin_amdgcn_sched_barrier(0)
#define BAR do { SB0; __builtin_amdgcn_s_barrier(); } while (0)
#define LGKM(N) do { asm volatile("s_waitcnt lgkmcnt(" #N ")" ::: "memory"); SB0; } while (0)
#define VMW(N)  do { asm volatile("s_waitcnt vmcnt(" #N ")"  ::: "memory"); SB0; } while (0)
#define PRIO1 __builtin_amdgcn_s_setprio(1)
#define PRIO0 __builtin_amdgcn_s_setprio(0)

#define DSR(dst, base, OFFS) \
    asm volatile("ds_read_b128 %0, %1 offset:" OFFS : "=v"(dst) : "v"(base))

// A quadrant read: 4 x b128.
#define RD_A(BASEV, Q, K, O0, O1, O2, O3)          \
  do {                                             \
    DSR(a##Q##k##K[0], BASEV, O0);                 \
    DSR(a##Q##k##K[1], BASEV, O1);                 \
    DSR(a##Q##k##K[2], BASEV, O2);                 \
    DSR(a##Q##k##K[3], BASEV, O3);                 \
  } while (0)

// B quadrant read: 2 x b128.
#define RD_B(BASEV, Q, K, O0, O1)                  \
  do {                                             \
    DSR(b##Q##k##K[0], BASEV, O0);                 \
    DSR(b##Q##k##K[1], BASEV, O1);                 \
  } while (0)

#define ACC1(QM, MM, QN, NN, KK)                                                 \
  acc[(QM) * 4 + (MM)][(QN) * 2 + (NN)] = __builtin_amdgcn_mfma_f32_16x16x32_bf16( \
      a##QM##k##KK[MM], b##QN##k##KK[NN], acc[(QM) * 4 + (MM)][(QN) * 2 + (NN)], 0, 0, 0)

#define MFMA8(QM, QN, KK)       \
  do {                          \
    PRIO1;                      \
    ACC1(QM, 0, QN, 0, KK);     \
    ACC1(QM, 0, QN, 1, KK);     \
    ACC1(QM, 1, QN, 0, KK);     \
    ACC1(QM, 1, QN, 1, KK);     \
    ACC1(QM, 2, QN, 0, KK);     \
    ACC1(QM, 2, QN, 1, KK);     \
    ACC1(QM, 3, QN, 0, KK);     \
    ACC1(QM, 3, QN, 1, KK);     \
    PRIO0;                      \
  } while (0)

// stage one half-tile (2 x global_load_lds dwordx4)
#define STAGE(SRC, MATOFF, H, DB, KT)                                                              \
  do {                                                                                             \
    __builtin_amdgcn_global_load_lds(                                                              \
        (__attribute__((address_space(1))) void*)((SRC) + (long)((H) * 128) * (K_DIM * 2) +        \
                                                  (long)(KT) * (BK * 2)),                          \
        (__attribute__((address_space(3))) void*)(lds + (DB) + (MATOFF) + (H) * 16384 + ldst),     \
        16, 0, 0);                                                                                 \
    __builtin_amdgcn_global_load_lds(                                                              \
        (__attribute__((address_space(1))) void*)((SRC) + (long)((H) * 128 + 64) * (K_DIM * 2) +   \
                                                  (long)(KT) * (BK * 2)),                          \
        (__attribute__((address_space(3))) void*)(lds + (DB) + (MATOFF) + (H) * 16384 + 8192 +     \
                                                  ldst),                                           \
        16, 0, 0);                                                                                 \
  } while (0)

// One K-tile, parity P (literal 0/1), next parity PN.
// Read lead = 2 phases; waits leave exactly the younger batches outstanding.
// Epochs (separated by BAR): {ph1,ph2} {ph3,ph4} {ph5,ph6} {ph7,ph8}.
#define TILE(P, PN, JJ)                                                           \
  do {                                                                            \
    const int jp1 = (JJ) + 1, jp2 = (JJ) + 2;                                     \
    /* ==== barrier 8'->1 ==== */                                                 \
    BAR;                                                                          \
    /* ph1: read b1k0 (uses B-h1(j), drained @VMW0 ph6(j-1)); stage B-h0(j+1);   \
       MFMA(0,0,k0) <- a0k0,b0k0 read @ph7(j-1) */                                \
    RD_B(ba##P##0, 1, 0, "4096", "6144");                                         \
    if (jp1 < NT) STAGE(Bsrc, 32768, 0, (PN) * 65536, jp1);                       \
    LGKM(6);                                                                      \
    MFMA8(0, 0, 0);                                                               \
    /* ph2: stage B-h1(j+1); MFMA(1,0,k0) <- a1k0 read @ph8(j-1) */               \
    if (jp1 < NT) STAGE(Bsrc, 32768, 1, (PN) * 65536, jp1);                       \
    LGKM(2);                                                                      \
    MFMA8(1, 0, 0);                                                               \
    /* ==== barrier 2->3 ==== */                                                  \
    BAR;                                                                          \
    /* ph3: read a0k1 + b1k1; MFMA(1,1,k0) <- b1k0 read @ph1 */                   \
    RD_A(aa##P##1, 0, 1, "0", "2048", "4096", "6144");                            \
    RD_B(ba##P##1, 1, 1, "4096", "6144");                                         \
    LGKM(6);                                                                      \
    MFMA8(1, 1, 0);                                                               \
    /* ph4: read a1k1; MFMA(0,1,k0) (operands already drained, no wait) */        \
    RD_A(aa##P##1, 1, 1, "8192", "10240", "12288", "14336");                      \
    MFMA8(0, 1, 0);                                                               \
    /* ==== barrier 4->5 ==== */                                                  \
    BAR;                                                                          \
    /* ph5: read b0k1; MFMA(0,1,k1) <- a0k1,b1k1 read @ph3 */                     \
    RD_B(ba##P##1, 0, 1, "0", "2048");                                            \
    LGKM(6);                                                                      \
    MFMA8(0, 1, 1);                                                               \
    /* ph6: MFMA(1,1,k1) <- a1k1 read @ph4; then VMW(0): drains A(j+1),B(j+1)     \
       (all >=4 phases old) so the 6->7 barrier publishes next-tile LDS */        \
    LGKM(2);                                                                      \
    MFMA8(1, 1, 1);                                                               \
    VMW(0);                                                                       \
    /* ==== barrier 6->7 ==== */                                                  \
    BAR;                                                                          \
    /* ph7: read next-tile a0k0,b0k0 (parity PN); stage A-h0(j+2)->P;             \
       MFMA(1,0,k1) <- b0k1 read @ph5 */                                          \
    if (jp1 < NT) {                                                               \
      RD_A(aa##PN##0, 0, 0, "0", "2048", "4096", "6144");                         \
      RD_B(ba##PN##0, 0, 0, "0", "2048");                                         \
    }                                                                             \
    if (jp2 < NT) STAGE(Asrc, 0, 0, (P) * 65536, jp2);                            \
    LGKM(6);                                                                      \
    MFMA8(1, 0, 1);                                                               \
    /* ph8: read next-tile a1k0; stage A-h1(j+2); MFMA(0,0,k1) (no wait) */       \
    if (jp1 < NT) RD_A(aa##PN##0, 1, 0, "8192", "10240", "12288", "14336");       \
    if (jp2 < NT) STAGE(Asrc, 0, 1, (P) * 65536, jp2);                            \
    MFMA8(0, 0, 1);                                                               \
  } while (0)

__global__ __launch_bounds__(512, 2) void gemm8p(const __bf16* __restrict__ A,
                                                 const __bf16* __restrict__ B,
                                                 float* __restrict__ C) {
    __shared__ __attribute__((aligned(128))) char lds[131072];

    // XCD-aware bijective swizzle: nwg = 512, divisible by 8
    const int nwg = (M_DIM / BM) * (N_DIM / BN);   // 512
    int bid = blockIdx.x;
    int sw  = (bid & 7) * (nwg >> 3) + (bid >> 3);
    int mt = sw >> 4, ntl = sw & 15;               // 32 x 16 tiles
    int bm0 = mt * BM, bn0 = ntl * BN;

    int tid  = threadIdx.x;
    int lane = tid & 63;
    int wid  = tid >> 6;
    int wr   = wid >> 2;      // 0..1  (M half)
    int wc   = wid & 3;       // 0..3  (N quarter)

    f32x4 acc[8][4];
    f32x4 vz = {0.f, 0.f, 0.f, 0.f};
#pragma unroll
    for (int m = 0; m < 8; ++m)
#pragma unroll
        for (int n = 0; n < 4; ++n) acc[m][n] = vz;

    // fragment registers (single-buffered; 2-phase-lead schedule keeps WAR legal:
    // every reg write is >=3 phases after that reg's last MFMA use)
    bf16x8 a0k0[4], a1k0[4], a0k1[4], a1k1[4];
    bf16x8 b0k0[2], b1k0[2], b0k1[2], b1k1[2];

    // ---- staging addressing (inverse-swizzled global source, linear dest) ----
    int srow  = tid >> 3;
    int scolb = ((tid & 7) ^ (srow & 7)) * 16;
    const char* Asrc = (const char*)(A + (long)(bm0 + srow) * K_DIM) + scolb;
    const char* Bsrc = (const char*)(B + (long)(bn0 + srow) * K_DIM) + scolb;
    int ldst = tid * 16;

    // ---- fragment-read addressing (swizzled), as addrspace(3) pointers ----
    int lrow = lane & 15;
    int rc0  = (((lane >> 4) ^ (lane & 7)) << 4);
    int rc1  = rc0 ^ 64;
    int aoff = wr * 16384 + lrow * 128;
    int boff = 32768 + (wc >> 1) * 16384 + ((wc & 1) * 64 + lrow) * 128;

    lds3_t aa00 = (lds3_t)(lds + aoff + rc0);
    lds3_t aa01 = (lds3_t)(lds + aoff + rc1);
    lds3_t aa10 = (lds3_t)(lds + 65536 + aoff + rc0);
    lds3_t aa11 = (lds3_t)(lds + 65536 + aoff + rc1);
    lds3_t ba00 = (lds3_t)(lds + boff + rc0);
    lds3_t ba01 = (lds3_t)(lds + boff + rc1);
    lds3_t ba10 = (lds3_t)(lds + 65536 + boff + rc0);
    lds3_t ba11 = (lds3_t)(lds + 65536 + boff + rc1);

    // ---- prologue ----
    // Stage tile0 (A,B) + tile1 (A halves); drain tile0 (VMW(2) leaves the
    // tile1-A pair in flight); publish; then emulate ph7'/ph8' read batches.
    STAGE(Asrc, 0,     0, 0, 0);
    STAGE(Asrc, 0,     1, 0, 0);
    STAGE(Bsrc, 32768, 0, 0, 0);
    STAGE(Bsrc, 32768, 1, 0, 0);
    STAGE(Asrc, 0,     0, 65536, 1);
    STAGE(Asrc, 0,     1, 65536, 1);
    VMW(2);
    BAR;
    RD_A(aa00, 0, 0, "0", "2048", "4096", "6144");   // batch "ph7'": a0k0(0)
    RD_B(ba00, 0, 0, "0", "2048");                   //              b0k0(0)
    RD_A(aa00, 1, 0, "8192", "10240", "12288", "14336");  // batch "ph8'": a1k0(0)

    for (int j = 0; j < NT; j += 2) {
        TILE(0, 1, j);
        TILE(1, 0, j + 1);
    }

    // ---- epilogue: C/D layout col = lane&15, row = (lane>>4)*4 + jj ----
    int crow0 = bm0 + wr * 128 + (lane >> 4) * 4;
    int ccol0 = bn0 + wc * 64 + (lane & 15);
#pragma unroll
    for (int m = 0; m < 8; ++m)
#pragma unroll
        for (int n = 0; n < 4; ++n) {
            long base = (long)(crow0 + m * 16) * N_DIM + (ccol0 + n * 16);
#pragma unroll
            for (int jj = 0; jj < 4; ++jj)
                C[base + (long)jj * N_DIM] = acc[m][n][jj];
        }
}

// ---------------- fallback (only if ws too small): fused naive -------------
__global__ __launch_bounds__(256) void gemm_fallback(const float* __restrict__ A,
                                                     const int* __restrict__ qw,
                                                     const float* __restrict__ sc,
                                                     const float* __restrict__ zr,
                                                     float* __restrict__ C) {
    __shared__ float Ash[16][17];
    __shared__ float Wsh[16][17];
    int tx = threadIdx.x & 15, ty = threadIdx.x >> 4;
    int m = blockIdx.y * 16 + ty;
    int n = blockIdx.x * 16 + tx;
    float s = 0.f;
    for (int k0 = 0; k0 < K_DIM; k0 += 16) {
        Ash[ty][tx] = A[(long)m * K_DIM + k0 + tx];
        {
            int nn = blockIdx.x * 16 + ty;
            int kk = k0 + tx;
            int q = qw[(long)nn * KHALF + (kk >> 1)];
            int nib = (kk & 1) ? ((q >> 4) & 0xF) : (q & 0xF);
            int g = kk >> 7;
            Wsh[ty][tx] = ((float)nib - zr[nn * NG + g]) * sc[nn * NG + g];
        }
        __syncthreads();
#pragma unroll
        for (int kk = 0; kk < 16; ++kk)
            s += Ash[ty][kk] * Wsh[tx][kk];
        __syncthreads();
    }
    C[(long)m * N_DIM + n] = s;
}

extern "C" void kernel_launch(void* const* d_in, const int* in_sizes, int n_in,
                              void* d_out, int out_size, void* d_ws, size_t ws_size,
                              hipStream_t stream) {
    const float* A  = (const float*)d_in[0];
    const int*   qw = (const int*)d_in[1];
    const float* sc = (const float*)d_in[2];
    const float* zr = (const float*)d_in[3];
    float* C = (float*)d_out;

    const size_t needA = (size_t)M_DIM * K_DIM * 2;   // 64 MiB
    const size_t needW = (size_t)N_DIM * K_DIM * 2;   // 32 MiB

    if (ws_size >= needA + needW) {
        __bf16* Ab = (__bf16*)d_ws;
        __bf16* Wb = (__bf16*)((char*)d_ws + needA);
        cvtA_kernel<<<2048, 256, 0, stream>>>(A, Ab, (long)M_DIM * K_DIM / 8);
        deqW_kernel<<<2048, 256, 0, stream>>>(qw, sc, zr, Wb);
        gemm8p<<<(M_DIM / BM) * (N_DIM / BN), 512, 0, stream>>>(Ab, Wb, C);
    } else {
        dim3 g(N_DIM / 16, M_DIM / 16);
        gemm_fallback<<<g, 256, 0, stream>>>(A, qw, sc, zr, C);
    }
}